// Round 1
// baseline (4515.204 us; speedup 1.0000x reference)
//
#include <hip/hip_runtime.h>

#define T_LEN 16384
#define BATCH 32
#define HID 32
#define L2E 1.44269504088896340736f

#if __has_builtin(__builtin_amdgcn_exp2f)
#define EXP2F(x) __builtin_amdgcn_exp2f(x)
#else
#define EXP2F(x) __exp2f(x)
#endif

#if __has_builtin(__builtin_amdgcn_rcpf)
#define RCPF(x) __builtin_amdgcn_rcpf(x)
#else
#define RCPF(x) (1.0f / (x))
#endif

__device__ __forceinline__ float rlane(float v, int lane) {
    return __int_as_float(__builtin_amdgcn_readlane(__float_as_int(v), lane));
}

// One wave per batch element. Lane j<32 owns gates (i_j, g_j); lane 32+j owns
// (f_j, o_j) plus the cell/hidden state (c_j, h_j). h is broadcast to all
// lanes through v_readlane -> SGPRs, so the recurrent dot products are
// v_fmac_f32 with a scalar h operand (no LDS round-trip on the critical path).
__global__ __launch_bounds__(64, 1)
void lstm_seq_kernel(const float* __restrict__ x,
                     const float* __restrict__ W_ih,
                     const float* __restrict__ W_hh,
                     const float* __restrict__ b_ih,
                     const float* __restrict__ b_hh,
                     const float* __restrict__ W_out,
                     const float* __restrict__ b_out,
                     float* __restrict__ out)
{
    const int b    = blockIdx.x;
    const int lane = threadIdx.x;
    const int j    = lane & 31;
    const bool upper = (lane >= 32);

    // torch gate order in W_ih/W_hh rows: [0,32)=i [32,64)=f [64,96)=g [96,128)=o
    const int rowA = upper ? (32 + j) : j;        // f : i   (both sigmoid)
    const int rowB = upper ? (96 + j) : (64 + j); // o : g   (sigmoid : tanh)

    // W_hh rows into registers (rows are 128B contiguous, 16B aligned)
    float Wa[HID], Wb[HID];
    const float4* Whh4 = reinterpret_cast<const float4*>(W_hh);
    #pragma unroll
    for (int q = 0; q < 8; ++q) {
        float4 va = Whh4[rowA * 8 + q];
        Wa[4*q+0] = va.x; Wa[4*q+1] = va.y; Wa[4*q+2] = va.z; Wa[4*q+3] = va.w;
        float4 vb = Whh4[rowB * 8 + q];
        Wb[4*q+0] = vb.x; Wb[4*q+1] = vb.y; Wb[4*q+2] = vb.z; Wb[4*q+3] = vb.w;
    }
    const float wihA = W_ih[rowA];
    const float wihB = W_ih[rowB];
    const float bA = b_ih[rowA] + b_hh[rowA];
    const float bB = b_ih[rowB] + b_hh[rowB];

    // B-gate activation: r = rcp(1 + exp2(-z*sB)); B = r*mB + aB
    //   lower (g, tanh):    sB = 2*log2e, mB = 2, aB = -1
    //   upper (o, sigmoid): sB =   log2e, mB = 1, aB =  0
    const float sB = upper ? L2E : (2.0f * L2E);
    const float mB = upper ? 1.0f : 2.0f;
    const float aB = upper ? 0.0f : -1.0f;

    const float wout = W_out[j];   // used by upper lanes
    const float bout = b_out[0];

    // Deferred-output history: row = step-in-chunk (stride 33 floats breaks
    // bank aliasing for the flush reads: bank = (33*l + k) % 32 = (l+k) % 32)
    __shared__ float phist[64 * 33];

    float hs[HID];
    #pragma unroll
    for (int k = 0; k < HID; ++k) hs[k] = 0.0f;
    float c = 0.0f;

    const float* xb = x + (size_t)b * T_LEN;
    float*       yb = out + (size_t)b * T_LEN;

    float xv = xb[lane];  // 64 timesteps of x per lane-chunk

    for (int t0 = 0; t0 < T_LEN; t0 += 64) {
        // prefetch next x chunk (consumed 64 steps from now)
        float xv_next = (t0 + 64 < T_LEN) ? xb[t0 + 64 + lane] : 0.0f;

        #pragma unroll 4
        for (int s = 0; s < 64; ++s) {
            const float xs = rlane(xv, s);
            float za = fmaf(xs, wihA, bA);
            float zb = fmaf(xs, wihB, bB);
            #pragma unroll
            for (int k = 0; k < HID; ++k) {
                za = fmaf(hs[k], Wa[k], za);   // v_fmac v, s_hk, v_Wa
                zb = fmaf(hs[k], Wb[k], zb);
            }
            // A = sigmoid(za)  (i on lower, f on upper)
            const float A  = RCPF(1.0f + EXP2F(-za * L2E));
            const float r  = RCPF(1.0f + EXP2F(-zb * sB));
            const float Bv = fmaf(r, mB, aB);  // tanh(g) : sigmoid(o)

            // lower lanes: u = sig(i)*tanh(g); ship to upper half
            const float u  = A * Bv;
            const float tu = __shfl_xor(u, 32, 64);

            // upper lanes: c = sig(f)*c + u ; h = sig(o)*tanh(c)
            // (lower lanes run the same ops on bounded garbage — harmless)
            c = fmaf(A, c, tu);
            const float th = fmaf(2.0f, RCPF(1.0f + EXP2F(-2.0f * L2E * c)), -1.0f);
            const float h  = Bv * th;

            if (upper) phist[s * 33 + j] = h * wout;

            // broadcast new h to SGPRs for the next step's dots
            #pragma unroll
            for (int k = 0; k < HID; ++k) hs[k] = rlane(h, 32 + k);
        }

        __syncthreads();  // single wave: cheap; makes phist writes visible
        float acc = bout;
        #pragma unroll
        for (int k = 0; k < HID; ++k) acc += phist[lane * 33 + k];
        yb[t0 + lane] = acc;
        __syncthreads();  // protect phist before next chunk rewrites it

        xv = xv_next;
    }
}

extern "C" void kernel_launch(void* const* d_in, const int* in_sizes, int n_in,
                              void* d_out, int out_size, void* d_ws, size_t ws_size,
                              hipStream_t stream) {
    const float* x     = (const float*)d_in[0];
    const float* W_ih  = (const float*)d_in[1];
    const float* W_hh  = (const float*)d_in[2];
    const float* b_ih  = (const float*)d_in[3];
    const float* b_hh  = (const float*)d_in[4];
    const float* W_out = (const float*)d_in[5];
    const float* b_out = (const float*)d_in[6];
    float* out = (float*)d_out;

    lstm_seq_kernel<<<BATCH, 64, 0, stream>>>(x, W_ih, W_hh, b_ih, b_hh,
                                              W_out, b_out, out);
}